// Round 4
// baseline (170.946 us; speedup 1.0000x reference)
//
#include <hip/hip_runtime.h>
#include <hip/hip_bf16.h>
#include <stdint.h>

// Problem constants (from reference)
#define B_N     2048
#define E_N     32
#define IN_N    2048
#define OUT_N   1024
#define TOPK    4

// GEMM tiling
#define BM      256
#define BN      128
#define BK      32
#define NT      (OUT_N / BN)        // 8 n-tiles
#define NKT     (IN_N / BK)         // 64 k-steps
#define THREADS 512                 // 8 waves, 2m x 4n, wave tile 128x32
#define MAX_SLOTS 64                // hard bound: sum ceil(c_e/256) <= 8192/256+32 = 64
#define GRID_GEMM (MAX_SLOTS * NT)  // 512

// ws layout (int words)
#define WS_COUNTS 0     // [32]
#define WS_NSLOTS 32    // [1]
#define WS_DESC   64    // [MAX_SLOTS]  packed (e<<6)|mt
#define WS_LISTS  256   // [E_N][B_N]   packed (b<<2)|k

typedef float  f32x4  __attribute__((ext_vector_type(4)));
typedef __bf16 bf16x8 __attribute__((ext_vector_type(8)));

union Pack8 { bf16x8 v; uint4 u; };

__device__ __forceinline__ uint4 pack8(f32x4 lo, f32x4 hi) {
  Pack8 p;
#pragma unroll
  for (int j = 0; j < 4; ++j) { p.v[j] = (__bf16)lo[j]; p.v[j + 4] = (__bf16)hi[j]; }
  return p.u;
}
__device__ __forceinline__ bf16x8 as_frag(uint4 u) { Pack8 p; p.u = u; return p.v; }

// ---------------- kernel 0: zero counters ----------------
__global__ void k_zero(int* __restrict__ ws) {
  if (threadIdx.x < 64) ws[threadIdx.x] = 0;
}

// ---------------- kernel 1: top-4-smallest + bucket ----------------
__global__ void k_topk(const float* __restrict__ act, int* __restrict__ ws) {
  int b = blockIdx.x * blockDim.x + threadIdx.x;
  if (b >= B_N) return;
  float v[E_N];
  const float* a = act + (size_t)b * E_N;
#pragma unroll
  for (int e = 0; e < E_N; ++e) v[e] = a[e];
  unsigned chosen = 0;
#pragma unroll
  for (int k = 0; k < TOPK; ++k) {
    float mv = 3.4e38f; int mi = 0;
#pragma unroll
    for (int e = 0; e < E_N; ++e) {
      bool sel = (((chosen >> e) & 1u) == 0u) && (v[e] < mv);  // strict <: stable (first index)
      mv = sel ? v[e] : mv;
      mi = sel ? e : mi;
    }
    chosen |= (1u << mi);
    int pos = atomicAdd(&ws[WS_COUNTS + mi], 1);
    ws[WS_LISTS + mi * B_N + pos] = (b << 2) | k;
  }
}

// ---------------- kernel 2: build tile worklist ----------------
__global__ void k_tiles(int* __restrict__ ws) {
  int e = threadIdx.x;  // launched with 64 (one wave)
  int c = (e < E_N) ? ws[WS_COUNTS + e] : 0;
  int t = (c + BM - 1) / BM;
  int off = 0, tot = 0;
  for (int j = 0; j < E_N; ++j) {
    int tj = __shfl(t, j, 64);
    if (j < e) off += tj;
    tot += tj;
  }
  if (e < E_N) {
    for (int i = 0; i < t; ++i) ws[WS_DESC + off + i] = (e << 6) | i;
  }
  if (e == 0) ws[WS_NSLOTS] = tot;
}

// ---------------- kernel 3: grouped GEMM (bf16 MFMA) ----------------
// 256x128 block tile, BK=32, reg prefetch + LDS dbuf, 1 barrier/K-step.
// 8 waves 2m x 4n; wave tile 128x32 (8x2 fragments).
// Mapping: slot&7 == XCD, nt-inner => the 8 nt-blocks of one expert-slot are
// dispatch-adjacent on ONE XCD: W read once (compulsory), A k-tiles L2-shared.
__global__ __launch_bounds__(THREADS, 2)
void k_gemm(const float* __restrict__ feat, const float* __restrict__ Wm,
            const float* __restrict__ bias, const int* __restrict__ ws,
            float* __restrict__ out) {
  int p = blockIdx.x;
  int j = p >> 3;
  int slot = (p & 7) + ((j >> 3) << 3);  // slot % 8 == XCD(p%8); bijective
  int nt   = j & 7;
  if (slot >= ws[WS_NSLOTS]) return;
  int desc = ws[WS_DESC + slot];
  int e = desc >> 6, mt = desc & 63;
  int count = ws[WS_COUNTS + e];
  int m0 = mt * BM;

  // LDS per buffer: A 1024 + W 512 uint4 slots (24KB); dbuf = 48KB
  __shared__ uint4 lds4[3072];
  __shared__ int gids[BM];

  int tid  = threadIdx.x;
  int lane = tid & 63;
  int wv   = tid >> 6;
  int wm   = wv >> 2;   // 0..1
  int wn   = wv & 3;    // 0..3

  // --- A staging: 2 threads/row, 16 floats each -> 2 bf16x8 slots ---
  int arow = tid >> 1, ah = tid & 1;
  int gid = -1;
  if (m0 + arow < count) gid = ws[WS_LISTS + e * B_N + m0 + arow];
  if (ah == 0) gids[arow] = gid;
  const float* aptr = feat + (size_t)(gid >> 2) * IN_N + ah * 16;  // deref'd only if gid>=0
  int a_wi0 = arow * 4 + ((ah * 2)     ^ ((arow >> 1) & 3));
  int a_wi1 = arow * 4 + ((ah * 2 + 1) ^ ((arow >> 1) & 3));

  // --- W staging: 4 threads/row, 8 floats each -> 1 slot ---
  int wrow = tid >> 2, kq = tid & 3;
  const float* wptr = Wm + ((size_t)e * OUT_N + (size_t)(nt * BN + wrow)) * IN_N + kq * 8;
  int w_wi = 1024 + wrow * 4 + (kq ^ ((wrow >> 1) & 3));

  // --- fragment read indices (uint4 units, swizzled) ---
  int aidx[8], bidx[2];
#pragma unroll
  for (int mi = 0; mi < 8; ++mi) {
    int r = wm * 128 + mi * 16 + (lane & 15);
    aidx[mi] = r * 4 + ((lane >> 4) ^ ((r >> 1) & 3));
  }
#pragma unroll
  for (int ni = 0; ni < 2; ++ni) {
    int r = wn * 32 + ni * 16 + (lane & 15);
    bidx[ni] = 1024 + r * 4 + ((lane >> 4) ^ ((r >> 1) & 3));
  }

  f32x4 ra[4], rw[2];
  const f32x4 zero4 = {0.f, 0.f, 0.f, 0.f};

#define LOAD_TILE(K0)                                                        \
  do {                                                                       \
    if (gid >= 0) {                                                          \
      ra[0] = *(const f32x4*)(aptr + (K0));                                  \
      ra[1] = *(const f32x4*)(aptr + (K0) + 4);                              \
      ra[2] = *(const f32x4*)(aptr + (K0) + 8);                              \
      ra[3] = *(const f32x4*)(aptr + (K0) + 12);                             \
    } else { ra[0] = zero4; ra[1] = zero4; ra[2] = zero4; ra[3] = zero4; }   \
    rw[0] = *(const f32x4*)(wptr + (K0));                                    \
    rw[1] = *(const f32x4*)(wptr + (K0) + 4);                                \
  } while (0)

#define WRITE_TILE(BUF)                                                      \
  do {                                                                       \
    lds4[(BUF) * 1536 + a_wi0] = pack8(ra[0], ra[1]);                        \
    lds4[(BUF) * 1536 + a_wi1] = pack8(ra[2], ra[3]);                        \
    lds4[(BUF) * 1536 + w_wi]  = pack8(rw[0], rw[1]);                        \
  } while (0)

  f32x4 acc[8][2] = {};  // [mi][ni]

  LOAD_TILE(0);
  WRITE_TILE(0);
  __syncthreads();

  int cur = 0;
#pragma unroll 1
  for (int kt = 0; kt < NKT; ++kt) {
    bool pf = (kt + 1 < NKT);
    if (pf) LOAD_TILE((kt + 1) * BK);   // issue next tile's loads first

    int base = cur * 1536;
    bf16x8 af[8], bfr[2];
#pragma unroll
    for (int mi = 0; mi < 8; ++mi) af[mi] = as_frag(lds4[base + aidx[mi]]);
#pragma unroll
    for (int ni = 0; ni < 2; ++ni) bfr[ni] = as_frag(lds4[base + bidx[ni]]);
#pragma unroll
    for (int mi = 0; mi < 8; ++mi)
#pragma unroll
      for (int ni = 0; ni < 2; ++ni)
        acc[mi][ni] = __builtin_amdgcn_mfma_f32_16x16x32_bf16(af[mi], bfr[ni], acc[mi][ni], 0, 0, 0);

    if (pf) WRITE_TILE(cur ^ 1);        // other buffer
    __syncthreads();                    // writes landed + all done reading cur
    cur ^= 1;
  }

  // --- epilogue: D row=(lane>>4)*4+j, col=lane&15 ---
#pragma unroll
  for (int ni = 0; ni < 2; ++ni) {
    int col = nt * BN + wn * 32 + ni * 16 + (lane & 15);
    float bs = bias[e * OUT_N + col];
#pragma unroll
    for (int mi = 0; mi < 8; ++mi) {
#pragma unroll
      for (int j2 = 0; j2 < 4; ++j2) {
        int g = gids[wm * 128 + mi * 16 + (lane >> 4) * 4 + j2];
        if (g >= 0) out[(size_t)g * OUT_N + col] = acc[mi][ni][j2] + bs;
      }
    }
  }
}

extern "C" void kernel_launch(void* const* d_in, const int* in_sizes, int n_in,
                              void* d_out, int out_size, void* d_ws, size_t ws_size,
                              hipStream_t stream) {
  const float* feat = (const float*)d_in[0];   // [B, IN]
  const float* Wm   = (const float*)d_in[1];   // [E, OUT, IN]
  const float* bias = (const float*)d_in[2];   // [E, OUT]
  const float* act  = (const float*)d_in[3];   // [B, E]
  int*   ws  = (int*)d_ws;
  float* out = (float*)d_out;

  hipLaunchKernelGGL(k_zero,  dim3(1),          dim3(64),      0, stream, ws);
  hipLaunchKernelGGL(k_topk,  dim3(B_N / 256),  dim3(256),     0, stream, act, ws);
  hipLaunchKernelGGL(k_tiles, dim3(1),          dim3(64),      0, stream, ws);
  hipLaunchKernelGGL(k_gemm,  dim3(GRID_GEMM),  dim3(THREADS), 0, stream,
                     feat, Wm, bias, ws, out);
}

// Round 5
// 154.654 us; speedup vs baseline: 1.1053x; 1.1053x over previous
//
#include <hip/hip_runtime.h>
#include <hip/hip_bf16.h>
#include <stdint.h>

// Problem constants (from reference)
#define B_N     2048
#define E_N     32
#define IN_N    2048
#define OUT_N   1024
#define TOPK    4

// GEMM tiling
#define BM      256
#define BN      256
#define BK      32
#define NT      (OUT_N / BN)        // 4 n-tiles
#define NKT     (IN_N / BK)         // 64 k-steps
#define THREADS 512                 // 8 waves, 2m x 4n, wave tile 128x64
#define MAX_SLOTS 64                // hard bound: sum ceil(c_e/256) <= 8192/256+32 = 64
#define GRID_GEMM (MAX_SLOTS * NT)  // 256

// ws layout (int words)
#define WS_COUNTS 0     // [32]
#define WS_NSLOTS 32    // [1]
#define WS_DESC   64    // [MAX_SLOTS]  packed (e<<6)|mt
#define WS_LISTS  256   // [E_N][B_N]   packed (b<<2)|k

typedef float  f32x4  __attribute__((ext_vector_type(4)));
typedef __bf16 bf16x8 __attribute__((ext_vector_type(8)));

union Pack8 { bf16x8 v; uint4 u; };

__device__ __forceinline__ uint4 pack8(f32x4 lo, f32x4 hi) {
  Pack8 p;
#pragma unroll
  for (int j = 0; j < 4; ++j) { p.v[j] = (__bf16)lo[j]; p.v[j + 4] = (__bf16)hi[j]; }
  return p.u;
}
__device__ __forceinline__ bf16x8 as_frag(uint4 u) { Pack8 p; p.u = u; return p.v; }

// ---------------- kernel 0: zero counters ----------------
__global__ void k_zero(int* __restrict__ ws) {
  if (threadIdx.x < 64) ws[threadIdx.x] = 0;
}

// ---------------- kernel 1: top-4-smallest + bucket ----------------
__global__ void k_topk(const float* __restrict__ act, int* __restrict__ ws) {
  int b = blockIdx.x * blockDim.x + threadIdx.x;
  if (b >= B_N) return;
  float v[E_N];
  const float* a = act + (size_t)b * E_N;
#pragma unroll
  for (int e = 0; e < E_N; ++e) v[e] = a[e];
  unsigned chosen = 0;
#pragma unroll
  for (int k = 0; k < TOPK; ++k) {
    float mv = 3.4e38f; int mi = 0;
#pragma unroll
    for (int e = 0; e < E_N; ++e) {
      bool sel = (((chosen >> e) & 1u) == 0u) && (v[e] < mv);  // strict <: stable (first index)
      mv = sel ? v[e] : mv;
      mi = sel ? e : mi;
    }
    chosen |= (1u << mi);
    int pos = atomicAdd(&ws[WS_COUNTS + mi], 1);
    ws[WS_LISTS + mi * B_N + pos] = (b << 2) | k;
  }
}

// ---------------- kernel 2: build tile worklist ----------------
__global__ void k_tiles(int* __restrict__ ws) {
  int e = threadIdx.x;  // launched with 64 (one wave)
  int c = (e < E_N) ? ws[WS_COUNTS + e] : 0;
  int t = (c + BM - 1) / BM;
  int off = 0, tot = 0;
  for (int j = 0; j < E_N; ++j) {
    int tj = __shfl(t, j, 64);
    if (j < e) off += tj;
    tot += tj;
  }
  if (e < E_N) {
    for (int i = 0; i < t; ++i) ws[WS_DESC + off + i] = (e << 6) | i;
  }
  if (e == 0) ws[WS_NSLOTS] = tot;
}

// ---------------- kernel 3: grouped GEMM (bf16 MFMA) ----------------
// 256x256 block tile, BK=32, reg prefetch + LDS dbuf, 1 barrier/K-step.
// 8 waves 2m x 4n; wave tile 128x64 (8x4 fragments, acc=128 -> AGPRs).
// Fabric-volume-minimal point under the acc-register wall:
// V = slots*8MB (W) + 256MB (A x4) + 32MB (out) ~= 672MB @ ~5.3 TB/s.
__global__ __launch_bounds__(THREADS, 2)
void k_gemm(const float* __restrict__ feat, const float* __restrict__ Wm,
            const float* __restrict__ bias, const int* __restrict__ ws,
            float* __restrict__ out) {
  // slot round-robin over XCDs: active slots (~48) spread evenly
  int p = blockIdx.x;
  int x = p & 7, j = p >> 3;     // x = XCD, j 0..31
  int slot = x + 8 * (j >> 2);   // 0..63, slot % 8 == XCD
  int nt   = j & 3;
  if (slot >= ws[WS_NSLOTS]) return;
  int desc = ws[WS_DESC + slot];
  int e = desc >> 6, mt = desc & 63;
  int count = ws[WS_COUNTS + e];
  int m0 = mt * BM;

  // LDS per buffer: A 1024 + W 1024 uint4 slots (32KB); dbuf = 64KB
  __shared__ uint4 lds4[4096];
  __shared__ int gids[BM];

  int tid  = threadIdx.x;
  int lane = tid & 63;
  int wv   = tid >> 6;
  int wm   = wv >> 2;   // 0..1
  int wn   = wv & 3;    // 0..3

  // --- A staging: 2 slots/thread (rows t>>2 and 128+(t>>2)), seg = t&3 ---
  int seg  = tid & 3;
  int ar0  = tid >> 2;          // 0..127
  int ar1  = 128 + (tid >> 2);  // 128..255
  int gid0 = -1, gid1 = -1;
  if (m0 + ar0 < count) gid0 = ws[WS_LISTS + e * B_N + m0 + ar0];
  if (m0 + ar1 < count) gid1 = ws[WS_LISTS + e * B_N + m0 + ar1];
  if (seg == 0) { gids[ar0] = gid0; gids[ar1] = gid1; }
  const float* aptr0 = feat + (size_t)(gid0 >> 2) * IN_N + seg * 8;  // deref'd only if gid>=0
  const float* aptr1 = feat + (size_t)(gid1 >> 2) * IN_N + seg * 8;
  int a_wi0 = ar0 * 4 + (seg ^ ((ar0 >> 1) & 3));
  int a_wi1 = ar1 * 4 + (seg ^ ((ar1 >> 1) & 3));

  // --- W staging: 2 slots/thread (rows t>>2 and 128+(t>>2)) ---
  int wr0 = tid >> 2, wr1 = 128 + (tid >> 2);
  const float* wptr0 = Wm + ((size_t)e * OUT_N + (size_t)(nt * BN + wr0)) * IN_N + seg * 8;
  const float* wptr1 = Wm + ((size_t)e * OUT_N + (size_t)(nt * BN + wr1)) * IN_N + seg * 8;
  int w_wi0 = 1024 + wr0 * 4 + (seg ^ ((wr0 >> 1) & 3));
  int w_wi1 = 1024 + wr1 * 4 + (seg ^ ((wr1 >> 1) & 3));

  // --- fragment read indices (uint4 units, swizzled) ---
  int aidx[8], bidx[4];
#pragma unroll
  for (int mi = 0; mi < 8; ++mi) {
    int r = wm * 128 + mi * 16 + (lane & 15);
    aidx[mi] = r * 4 + ((lane >> 4) ^ ((r >> 1) & 3));
  }
#pragma unroll
  for (int ni = 0; ni < 4; ++ni) {
    int r = wn * 64 + ni * 16 + (lane & 15);
    bidx[ni] = 1024 + r * 4 + ((lane >> 4) ^ ((r >> 1) & 3));
  }

  f32x4 ra[4], rw[4];
  const f32x4 zero4 = {0.f, 0.f, 0.f, 0.f};

#define LOAD_TILE(K0)                                                        \
  do {                                                                       \
    if (gid0 >= 0) {                                                         \
      ra[0] = *(const f32x4*)(aptr0 + (K0));                                 \
      ra[1] = *(const f32x4*)(aptr0 + (K0) + 4);                             \
    } else { ra[0] = zero4; ra[1] = zero4; }                                 \
    if (gid1 >= 0) {                                                         \
      ra[2] = *(const f32x4*)(aptr1 + (K0));                                 \
      ra[3] = *(const f32x4*)(aptr1 + (K0) + 4);                             \
    } else { ra[2] = zero4; ra[3] = zero4; }                                 \
    rw[0] = *(const f32x4*)(wptr0 + (K0));                                   \
    rw[1] = *(const f32x4*)(wptr0 + (K0) + 4);                               \
    rw[2] = *(const f32x4*)(wptr1 + (K0));                                   \
    rw[3] = *(const f32x4*)(wptr1 + (K0) + 4);                               \
  } while (0)

#define WRITE_TILE(BUF)                                                      \
  do {                                                                       \
    lds4[(BUF) * 2048 + a_wi0] = pack8(ra[0], ra[1]);                        \
    lds4[(BUF) * 2048 + a_wi1] = pack8(ra[2], ra[3]);                        \
    lds4[(BUF) * 2048 + w_wi0] = pack8(rw[0], rw[1]);                        \
    lds4[(BUF) * 2048 + w_wi1] = pack8(rw[2], rw[3]);                        \
  } while (0)

  f32x4 acc[8][4] = {};  // [mi][ni] -> 128 AGPRs

  LOAD_TILE(0);
  WRITE_TILE(0);
  __syncthreads();

  int cur = 0;
#pragma unroll 1
  for (int kt = 0; kt < NKT; ++kt) {
    bool pf = (kt + 1 < NKT);
    if (pf) LOAD_TILE((kt + 1) * BK);   // issue next tile's loads first

    int base = cur * 2048;
    bf16x8 af[8], bfr[4];
#pragma unroll
    for (int mi = 0; mi < 8; ++mi) af[mi] = as_frag(lds4[base + aidx[mi]]);
#pragma unroll
    for (int ni = 0; ni < 4; ++ni) bfr[ni] = as_frag(lds4[base + bidx[ni]]);
#pragma unroll
    for (int mi = 0; mi < 8; ++mi)
#pragma unroll
      for (int ni = 0; ni < 4; ++ni)
        acc[mi][ni] = __builtin_amdgcn_mfma_f32_16x16x32_bf16(af[mi], bfr[ni], acc[mi][ni], 0, 0, 0);

    if (pf) WRITE_TILE(cur ^ 1);        // other buffer
    __syncthreads();                    // writes landed + all done reading cur
    cur ^= 1;
  }

  // --- epilogue: D row=(lane>>4)*4+j, col=lane&15 ---
#pragma unroll
  for (int ni = 0; ni < 4; ++ni) {
    int col = nt * BN + wn * 64 + ni * 16 + (lane & 15);
    float bs = bias[e * OUT_N + col];
#pragma unroll
    for (int mi = 0; mi < 8; ++mi) {
#pragma unroll
      for (int j2 = 0; j2 < 4; ++j2) {
        int g = gids[wm * 128 + mi * 16 + (lane >> 4) * 4 + j2];
        if (g >= 0) out[(size_t)g * OUT_N + col] = acc[mi][ni][j2] + bs;
      }
    }
  }
}

extern "C" void kernel_launch(void* const* d_in, const int* in_sizes, int n_in,
                              void* d_out, int out_size, void* d_ws, size_t ws_size,
                              hipStream_t stream) {
  const float* feat = (const float*)d_in[0];   // [B, IN]
  const float* Wm   = (const float*)d_in[1];   // [E, OUT, IN]
  const float* bias = (const float*)d_in[2];   // [E, OUT]
  const float* act  = (const float*)d_in[3];   // [B, E]
  int*   ws  = (int*)d_ws;
  float* out = (float*)d_out;

  hipLaunchKernelGGL(k_zero,  dim3(1),          dim3(64),      0, stream, ws);
  hipLaunchKernelGGL(k_topk,  dim3(B_N / 256),  dim3(256),     0, stream, act, ws);
  hipLaunchKernelGGL(k_tiles, dim3(1),          dim3(64),      0, stream, ws);
  hipLaunchKernelGGL(k_gemm,  dim3(GRID_GEMM),  dim3(THREADS), 0, stream,
                     feat, Wm, bias, ws, out);
}